// Round 1
// baseline (204.870 us; speedup 1.0000x reference)
//
#include <hip/hip_runtime.h>
#include <hip/hip_bf16.h>
#include <cstdint>
#include <cstddef>

#define B_N   32
#define CIN_  128
#define COUT_ 128
#define KW_   7
#define L_    4096
#define PAD_  3
#define NW_   128     // w-positions per block tile
#define BC_   32      // channels per K-chunk
#define NPOS_ 136     // sX rows (134 used, padded to 136)
#define XP_   40      // sX row pitch in elements (80 B = 20-bank stride)

typedef __attribute__((ext_vector_type(8))) short bf16x8;   // 8 bf16 in 4 VGPRs
typedef __attribute__((ext_vector_type(4))) float f32x4;

__device__ __forceinline__ void gl2lds16(const void* g, void* l) {
    __builtin_amdgcn_global_load_lds(
        (const __attribute__((address_space(1))) unsigned int*)g,
        (__attribute__((address_space(3))) unsigned int*)l, 16, 0, 0);
}

// ewb[k][o][c] = bf16(exp(W[o][c][k]))  -- A-operand staging layout
__global__ void prep_weight_kernel(const float* __restrict__ w,
                                   __hip_bfloat16* __restrict__ ewb) {
    int idx = blockIdx.x * 256 + threadIdx.x;
    if (idx >= KW_ * COUT_ * CIN_) return;
    int c    = idx & (CIN_ - 1);
    int rest = idx >> 7;
    int o    = rest & (COUT_ - 1);
    int k    = rest >> 7;
    float v = w[(o * CIN_ + c) * KW_ + k];
    ewb[idx] = __float2bfloat16(expf(v));
}

__global__ __launch_bounds__(256) void tropconv_kernel(
        const float* __restrict__ x,
        const __hip_bfloat16* __restrict__ ewb,
        const float* __restrict__ bias,
        float* __restrict__ out) {
    // sW: up-to-4 taps x 128 cout x 32 ch (c-blocks XOR-swizzled within each o-row)
    __shared__ __align__(16) __hip_bfloat16 sW[4 * COUT_ * BC_];   // 32768 B
    __shared__ __align__(16) __hip_bfloat16 sX[NPOS_ * XP_];       // 10880 B

    const int tid  = threadIdx.x;
    const int lane = tid & 63;
    const int wave = tid >> 6;
    const int wm   = wave >> 1;   // cout half (0/1)
    const int wn   = wave & 1;    // w half (0/1)
    const int l15  = lane & 15;
    const int q    = lane >> 4;

    const int b  = blockIdx.y;
    const int w0 = blockIdx.x * NW_;

    f32x4 acc[4][4];
    #pragma unroll
    for (int i = 0; i < 4; ++i)
        #pragma unroll
        for (int j = 0; j < 4; ++j)
            acc[i][j] = (f32x4){0.f, 0.f, 0.f, 0.f};

    const float* xb = x + (size_t)b * CIN_ * L_;

    for (int c0 = 0; c0 < CIN_; c0 += BC_) {
        // ---- stage sX[p][ci] = bf16(exp(x[b][c0+ci][w0-3+p])), 0 outside [0,L)
        for (int idx = tid; idx < BC_ * NPOS_; idx += 256) {
            int ci = idx / NPOS_;
            int p  = idx - ci * NPOS_;
            int gw = w0 - PAD_ + p;
            float e = 0.f;
            if (p < (NW_ + KW_ - 1) && (unsigned)gw < (unsigned)L_)
                e = expf(xb[(size_t)(c0 + ci) * L_ + gw]);
            sX[p * XP_ + ci] = __float2bfloat16(e);
        }

        #pragma unroll
        for (int g = 0; g < 2; ++g) {
            const int kbase = g ? 4 : 0;
            const int ntap  = g ? 3 : 4;

            // ---- stage sW via async global->LDS, 16 B/lane, contiguous LDS.
            // 16B granule e16 -> (t = e16>>9, o = (e16>>2)&127, slot = e16&3);
            // slot holds data c-block (slot ^ ((o>>1)&3)) to spread read banks.
            const int nPer = ntap * 2;   // wave-instructions per wave
            for (int i = 0; i < nPer; ++i) {
                int e16   = (wave * nPer + i) * 64 + lane;
                int jslot = e16 & 3;
                int o     = (e16 >> 2) & (COUT_ - 1);
                int t     = e16 >> 9;
                int jdata = jslot ^ ((o >> 1) & 3);
                const __hip_bfloat16* gsrc =
                    ewb + (((size_t)(kbase + t) * COUT_ + o) * CIN_ + c0 + jdata * 8);
                gl2lds16(gsrc, &sW[e16 * 8]);
            }
            __syncthreads();   // drains sX ds_writes + sW global_load_lds

            #pragma unroll
            for (int t = 0; t < ntap; ++t) {
                bf16x8 af[4], bx[4];
                #pragma unroll
                for (int mi = 0; mi < 4; ++mi) {
                    int o   = wm * 64 + mi * 16 + l15;          // A: m = lane&15
                    int blk = q ^ ((o >> 1) & 3);               // un-swizzle
                    af[mi] = *(const bf16x8*)&sW[(t * COUT_ + o) * BC_ + blk * 8];
                }
                #pragma unroll
                for (int ni = 0; ni < 4; ++ni) {
                    // output w index n = wn*64+ni*16+lane&15; input p = n + tap
                    int p = wn * 64 + ni * 16 + l15 + kbase + t;
                    bx[ni] = *(const bf16x8*)&sX[p * XP_ + q * 8];
                }
                #pragma unroll
                for (int mi = 0; mi < 4; ++mi)
                    #pragma unroll
                    for (int ni = 0; ni < 4; ++ni)
                        acc[mi][ni] = __builtin_amdgcn_mfma_f32_16x16x32_bf16(
                            af[mi], bx[ni], acc[mi][ni], 0, 0, 0);
            }
            __syncthreads();   // protect sW (and sX on last group) before restage
        }
    }

    // ---- epilogue: y = log(s) + bias[o]; C/D: col=lane&15 (w), row=q*4+reg (cout)
    float* outb = out + (size_t)b * COUT_ * L_;
    #pragma unroll
    for (int mi = 0; mi < 4; ++mi) {
        #pragma unroll
        for (int r = 0; r < 4; ++r) {
            int o = wm * 64 + mi * 16 + q * 4 + r;
            float bv = bias[o];
            #pragma unroll
            for (int ni = 0; ni < 4; ++ni) {
                int w = w0 + wn * 64 + ni * 16 + l15;
                outb[(size_t)o * L_ + w] = __logf(acc[mi][ni][r]) + bv;
            }
        }
    }
}

extern "C" void kernel_launch(void* const* d_in, const int* in_sizes, int n_in,
                              void* d_out, int out_size, void* d_ws, size_t ws_size,
                              hipStream_t stream) {
    const float* x    = (const float*)d_in[0];   // (32,128,4096) f32
    const float* wgt  = (const float*)d_in[1];   // (128,128,7)   f32
    const float* bias = (const float*)d_in[2];   // (128,)        f32
    float* out = (float*)d_out;                  // (32,128,4096) f32
    __hip_bfloat16* ewb = (__hip_bfloat16*)d_ws; // 229376 B scratch

    prep_weight_kernel<<<(KW_ * COUT_ * CIN_ + 255) / 256, 256, 0, stream>>>(wgt, ewb);
    tropconv_kernel<<<dim3(L_ / NW_, B_N), 256, 0, stream>>>(x, ewb, bias, out);
}

// Round 3
// 202.988 us; speedup vs baseline: 1.0093x; 1.0093x over previous
//
#include <hip/hip_runtime.h>
#include <hip/hip_bf16.h>
#include <cstdint>
#include <cstddef>
#include <cmath>

#define B_N   32
#define CIN_  128
#define COUT_ 128
#define KW_   7
#define L_    4096
#define PAD_  3
#define NW_   128     // w-positions per block tile
#define BC_   32      // channels per K-chunk
#define NPOSU 134     // used sX rows (NW + KW - 1)
#define NPOS_ 136     // staged sX rows (padded)
#define XP_   40      // sX row pitch in elements (80 B)
#define NTASK 544     // NPOS_ * 4 channel-granules

typedef __attribute__((ext_vector_type(8))) short bf16x8;   // 8 bf16 in 4 VGPRs
typedef __attribute__((ext_vector_type(4))) float f32x4;

// ewb[k][o][c] = bf16(exp(W[o][c][k]))  -- A-fragment-friendly layout
__global__ void prep_weight_kernel(const float* __restrict__ w,
                                   __hip_bfloat16* __restrict__ ewb) {
    int idx = blockIdx.x * 256 + threadIdx.x;
    if (idx >= KW_ * COUT_ * CIN_) return;
    int c    = idx & (CIN_ - 1);
    int rest = idx >> 7;
    int o    = rest & (COUT_ - 1);
    int k    = rest >> 7;
    ewb[idx] = __float2bfloat16(__expf(w[(o * CIN_ + c) * KW_ + k]));
}

// ---- x staging, split into load (global, issued a chunk ahead) and
// ---- store (exp + pack + ds_write_b128, after the MFMAs consume latency).
// Invalid (padding) positions carry -INF so the deferred exp yields exactly 0.
__device__ __forceinline__ void stage_load(const float* __restrict__ xb,
                                           int c0, int w0, int tid,
                                           float e[3][8]) {
    #pragma unroll
    for (int s = 0; s < 3; ++s) {
        int tau = tid + 256 * s;
        if (tau < NTASK) {
            int p  = tau % NPOS_;          // lane-consecutive -> coalesced loads
            int g  = tau / NPOS_;          // channel granule (8 ch)
            int gw = w0 - PAD_ + p;
            bool v = (p < NPOSU) && ((unsigned)gw < (unsigned)L_);
            int gwc = gw < 0 ? 0 : (gw >= L_ ? L_ - 1 : gw);   // in-bounds addr
            const float* src = xb + (size_t)(c0 + g * 8) * L_ + gwc;
            #pragma unroll
            for (int j = 0; j < 8; ++j) {
                float t = src[(size_t)j * L_];
                e[s][j] = v ? t : -INFINITY;   // exp(-inf)=0 => true zero-pad
            }
        }
    }
}

__device__ __forceinline__ void stage_store(__hip_bfloat16* __restrict__ buf,
                                            int tid, const float e[3][8]) {
    #pragma unroll
    for (int s = 0; s < 3; ++s) {
        int tau = tid + 256 * s;
        if (tau < NTASK) {
            int p = tau % NPOS_;
            int g = tau / NPOS_;
            bf16x8 v;
            #pragma unroll
            for (int j = 0; j < 8; ++j)
                ((__hip_bfloat16*)&v)[j] = __float2bfloat16(__expf(e[s][j]));
            *(bf16x8*)&buf[p * XP_ + g * 8] = v;   // 80B p-stride: 8 bank-starts
        }
    }
}

__global__ __launch_bounds__(256, 3) void tropconv_kernel(
        const float* __restrict__ x,
        const __hip_bfloat16* __restrict__ ewb,
        const float* __restrict__ bias,
        float* __restrict__ out) {
    __shared__ __align__(16) __hip_bfloat16 sX[2][NPOS_ * XP_];   // 2 x 10880 B

    const int tid  = threadIdx.x;
    const int lane = tid & 63;
    const int wave = tid >> 6;
    const int wm   = wave >> 1;   // cout half (0/1)
    const int wn   = wave & 1;    // w half (0/1)
    const int l15  = lane & 15;
    const int q    = lane >> 4;

    const int b  = blockIdx.y;
    const int w0 = blockIdx.x * NW_;

    f32x4 acc[4][4];
    #pragma unroll
    for (int i = 0; i < 4; ++i)
        #pragma unroll
        for (int j = 0; j < 4; ++j)
            acc[i][j] = (f32x4){0.f, 0.f, 0.f, 0.f};

    const float* xb = x + (size_t)b * CIN_ * L_;

    // raw x values kept in VGPRs; exp happens in stage_store (loads long done)
    float e[3][8];
    stage_load(xb, 0, w0, tid, e);
    stage_store(&sX[0][0], tid, e);       // chunk 0 -> buf 0
    stage_load(xb, BC_, w0, tid, e);      // chunk 1 loads in flight

    for (int c = 0; c < 4; ++c) {
        __syncthreads();
        const int c0 = c * BC_;
        const __hip_bfloat16* buf = &sX[c & 1][0];

        #pragma unroll
        for (int t = 0; t < KW_; ++t) {
            bf16x8 af[4], bx[4];
            #pragma unroll
            for (int mi = 0; mi < 4; ++mi) {
                int o = wm * 64 + mi * 16 + l15;       // A: m = lane&15
                af[mi] = *(const bf16x8*)(ewb + ((size_t)t * COUT_ + o) * CIN_
                                          + c0 + q * 8);   // L2-resident
            }
            #pragma unroll
            for (int ni = 0; ni < 4; ++ni) {
                int p = wn * 64 + ni * 16 + l15 + t;   // input pos = out w + tap
                bx[ni] = *(const bf16x8*)&buf[p * XP_ + q * 8];
            }
            #pragma unroll
            for (int mi = 0; mi < 4; ++mi)
                #pragma unroll
                for (int ni = 0; ni < 4; ++ni)
                    acc[mi][ni] = __builtin_amdgcn_mfma_f32_16x16x32_bf16(
                        af[mi], bx[ni], acc[mi][ni], 0, 0, 0);
        }

        if (c < 3) {
            stage_store(&sX[(c + 1) & 1][0], tid, e);  // chunk c+1 -> other buf
            if (c < 2)
                stage_load(xb, (c + 2) * BC_, w0, tid, e);  // prefetch chunk c+2
        }
    }

    // ---- epilogue: y = log(s) + bias[o]; C/D: col=lane&15 (w), row=q*4+reg
    float* outb = out + (size_t)b * COUT_ * L_;
    #pragma unroll
    for (int mi = 0; mi < 4; ++mi) {
        #pragma unroll
        for (int r = 0; r < 4; ++r) {
            int o = wm * 64 + mi * 16 + q * 4 + r;
            float bv = bias[o];
            #pragma unroll
            for (int ni = 0; ni < 4; ++ni) {
                int w = w0 + wn * 64 + ni * 16 + l15;
                outb[(size_t)o * L_ + w] = __logf(acc[mi][ni][r]) + bv;
            }
        }
    }
}

extern "C" void kernel_launch(void* const* d_in, const int* in_sizes, int n_in,
                              void* d_out, int out_size, void* d_ws, size_t ws_size,
                              hipStream_t stream) {
    const float* x    = (const float*)d_in[0];   // (32,128,4096) f32
    const float* wgt  = (const float*)d_in[1];   // (128,128,7)   f32
    const float* bias = (const float*)d_in[2];   // (128,)        f32
    float* out = (float*)d_out;                  // (32,128,4096) f32
    __hip_bfloat16* ewb = (__hip_bfloat16*)d_ws; // 229376 B scratch

    prep_weight_kernel<<<(KW_ * COUT_ * CIN_ + 255) / 256, 256, 0, stream>>>(wgt, ewb);
    tropconv_kernel<<<dim3(L_ / NW_, B_N), 256, 0, stream>>>(x, ewb, bias, out);
}